// Round 1
// baseline (461.216 us; speedup 1.0000x reference)
//
#include <hip/hip_runtime.h>
#include <stdint.h>

typedef int i32x4 __attribute__((ext_vector_type(4)));
typedef unsigned short u16x8 __attribute__((ext_vector_type(8)));

#define N_TOK 2048
#define HID   4096
#define INTER 11008
#define TWOI  22016
#define KT1   32      // HID/128
#define KT2   86      // INTER/128
#define NT1   172     // TWOI/128
#define NT2   32      // HID/128
#define MTI   16      // N_TOK/128

#define GLD16(gp, lp) __builtin_amdgcn_global_load_lds( \
    (const __attribute__((address_space(1))) void*)(gp), \
    (__attribute__((address_space(3))) void*)(lp), 16, 0, 0)

__device__ __forceinline__ unsigned short f2bf(float f) {
  uint32_t u = __float_as_uint(f);
  uint32_t r = (u + 0x7fffu + ((u >> 16) & 1u)) >> 16;
  return (unsigned short)r;
}

__device__ __forceinline__ float bf2f(unsigned short b) {
  return __uint_as_float(((uint32_t)b) << 16);
}

// ---------------------------------------------------------------------------
// Pack int32 [R][K] -> int8 tiled [R/128][K/128][128][128], interior bytes
// stored pre-XOR-swizzled: stored[row][c'] = src[row][c' ^ ((row&7)<<4)]
// so that GEMM LDS staging is a linear copy and swizzled ds_read_b128 is
// bank-conflict-free.
// ---------------------------------------------------------------------------
__global__ __launch_bounds__(256) void pack_tiled(
    const int* __restrict__ src, uint8_t* __restrict__ dst, int K, int KT)
{
  const long u = (long)blockIdx.x * 256 + threadIdx.x;  // one 16B unit each
  const long tile = u >> 10;                            // 1024 units / tile
  const int within = (int)(u & 1023);
  const int row = within >> 3;
  const int swc = (within & 7) << 4;                    // stored col base
  const int col = swc ^ ((row & 7) << 4);               // source col base
  const long tR = tile / KT;
  const long tK = tile - tR * KT;
  const int* s = src + (tR * 128 + row) * (long)K + tK * 128 + col;
  i32x4 o;
#pragma unroll
  for (int q = 0; q < 4; ++q) {
    i32x4 w = *reinterpret_cast<const i32x4*>(s + q * 4);
    o[q] = (w[0] & 255) | ((w[1] & 255) << 8) | ((w[2] & 255) << 16)
         | ((w[3] & 255) << 24);
  }
  *reinterpret_cast<i32x4*>(dst + tile * 16384 + (long)within * 16) = o;
}

// ---------------------------------------------------------------------------
// GEMM core macros (m97 structure, int8 MFMA 16x16x64, 128x128 tile, BK=128)
// ---------------------------------------------------------------------------
#define GEMM_PROLOGUE(AT, BT, KT)                                              \
  __shared__ uint8_t As[16384];                                                \
  __shared__ uint8_t Bs[16384];                                                \
  const int tid = threadIdx.x;                                                 \
  const int lane = tid & 63, wid = tid >> 6;                                   \
  const int mt = blockIdx.x, nt = blockIdx.y;                                  \
  const uint8_t* ga = (AT) + ((size_t)mt * (KT)) * 16384 + wid * 1024 + lane * 16; \
  const uint8_t* gb = (BT) + ((size_t)nt * (KT)) * 16384 + wid * 1024 + lane * 16; \
  uint8_t* lA = &As[wid * 1024 + lane * 16];                                   \
  uint8_t* lB = &Bs[wid * 1024 + lane * 16];                                   \
  const int r15 = lane & 15, g16 = (lane >> 4) << 4;                           \
  const int wm = (wid >> 1) << 6, wn = (wid & 1) << 6;                         \
  int rA[4], sA[4], rB[4], sB[4];                                              \
  _Pragma("unroll")                                                            \
  for (int m = 0; m < 4; ++m) {                                                \
    int ra = wm + m * 16 + r15;                                                \
    rA[m] = ra * 128; sA[m] = (ra & 7) << 4;                                   \
    int rb = wn + m * 16 + r15;                                                \
    rB[m] = rb * 128; sB[m] = (rb & 7) << 4;                                   \
  }                                                                            \
  i32x4 acc[4][4] = {};                                                        \
  for (int kt = 0; kt < (KT); ++kt) {                                          \
    _Pragma("unroll")                                                          \
    for (int i = 0; i < 4; ++i) {                                              \
      GLD16(ga + i * 4096, lA + i * 4096);                                     \
      GLD16(gb + i * 4096, lB + i * 4096);                                     \
    }                                                                          \
    ga += 16384; gb += 16384;                                                  \
    __syncthreads();                                                           \
    _Pragma("unroll")                                                          \
    for (int kk = 0; kk < 2; ++kk) {                                           \
      const int cK = g16 + kk * 64;                                            \
      i32x4 av[4], bv[4];                                                      \
      _Pragma("unroll")                                                        \
      for (int m = 0; m < 4; ++m)                                              \
        av[m] = *reinterpret_cast<const i32x4*>(&As[rA[m] + (cK ^ sA[m])]);    \
      _Pragma("unroll")                                                        \
      for (int n = 0; n < 4; ++n)                                              \
        bv[n] = *reinterpret_cast<const i32x4*>(&Bs[rB[n] + (cK ^ sB[n])]);    \
      _Pragma("unroll")                                                        \
      for (int m = 0; m < 4; ++m)                                              \
        _Pragma("unroll")                                                      \
        for (int n = 0; n < 4; ++n)                                            \
          acc[m][n] = __builtin_amdgcn_mfma_i32_16x16x64_i8(av[m], bv[n],      \
                                                            acc[m][n], 0, 0, 0); \
    }                                                                          \
    __syncthreads();                                                           \
  }                                                                            \
  const int crow0 = mt * 128 + wm + ((lane >> 4) << 2);                        \
  const int ccol0 = nt * 128 + wn + r15;

// GEMM1: C[row][col] = acc * xs[row] * wgs[col]  -> bf16 gateup [N][2I]
__global__ __launch_bounds__(256, 2) void gemm1_k(
    const uint8_t* __restrict__ At, const uint8_t* __restrict__ Bt,
    const float* __restrict__ xs, const float* __restrict__ wgs,
    unsigned short* __restrict__ gu)
{
  GEMM_PROLOGUE(At, Bt, KT1)
#pragma unroll
  for (int m = 0; m < 4; ++m) {
#pragma unroll
    for (int r = 0; r < 4; ++r) {
      const int row = crow0 + m * 16 + r;
      const float xr = xs[row];
      unsigned short* op = gu + (size_t)row * TWOI + ccol0;
#pragma unroll
      for (int n = 0; n < 4; ++n) {
        float v = (float)acc[m][n][r] * xr * wgs[ccol0 + n * 16];
        op[n * 16] = f2bf(v);
      }
    }
  }
}

// GEMM2: out[row][col] = acc * s2[row] * wds[col]  -> f32 [N][H]
__global__ __launch_bounds__(256, 2) void gemm2_k(
    const uint8_t* __restrict__ At, const uint8_t* __restrict__ Bt,
    const float* __restrict__ mx, const float* __restrict__ wds,
    float* __restrict__ out)
{
  GEMM_PROLOGUE(At, Bt, KT2)
#pragma unroll
  for (int m = 0; m < 4; ++m) {
#pragma unroll
    for (int r = 0; r < 4; ++r) {
      const int row = crow0 + m * 16 + r;
      const float s2 = mx[row] * (1.0f / 127.0f);
      float* op = out + (size_t)row * HID + ccol0;
#pragma unroll
      for (int n = 0; n < 4; ++n)
        op[n * 16] = (float)acc[m][n][r] * s2 * wds[ccol0 + n * 16];
    }
  }
}

// ---------------------------------------------------------------------------
// rowmax: one block per token row; m = max(|silu(g)*u|) over I columns
// ---------------------------------------------------------------------------
__global__ __launch_bounds__(256) void rowmax_k(
    const unsigned short* __restrict__ gu, float* __restrict__ mx)
{
  const int row = blockIdx.x;
  const unsigned short* gp = gu + (size_t)row * TWOI;
  float m = 0.f;
  for (int i = threadIdx.x; i < INTER / 8; i += 256) {
    u16x8 gv = *reinterpret_cast<const u16x8*>(gp + i * 8);
    u16x8 uv = *reinterpret_cast<const u16x8*>(gp + INTER + i * 8);
#pragma unroll
    for (int j = 0; j < 8; ++j) {
      float gf = bf2f(gv[j]);
      float uf = bf2f(uv[j]);
      float a = (gf / (1.f + __expf(-gf))) * uf;
      m = fmaxf(m, __builtin_fabsf(a));
    }
  }
#pragma unroll
  for (int o = 32; o; o >>= 1) m = fmaxf(m, __shfl_xor(m, o, 64));
  __shared__ float red[4];
  const int lane = threadIdx.x & 63, wid = threadIdx.x >> 6;
  if (lane == 0) red[wid] = m;
  __syncthreads();
  if (threadIdx.x == 0)
    mx[row] = fmaxf(fmaxf(red[0], red[1]), fmaxf(red[2], red[3]));
}

// ---------------------------------------------------------------------------
// quantize: recompute act, q2 = clip(rint(act*127/mx)); write int8 into
// tiled+swizzled layout for GEMM2's A operand. One 16B unit per thread.
// ---------------------------------------------------------------------------
__global__ __launch_bounds__(256) void quant_k(
    const unsigned short* __restrict__ gu, const float* __restrict__ mx,
    uint8_t* __restrict__ q2t)
{
  const long u = (long)blockIdx.x * 256 + threadIdx.x;
  const long tile = u >> 10;
  const int within = (int)(u & 1023);
  const int row = within >> 3;
  const int swc = (within & 7) << 4;
  const int col = swc ^ ((row & 7) << 4);
  const long tR = tile / KT2;
  const long tK = tile - tR * KT2;
  const int grow = (int)tR * 128 + row;
  const int gcol = (int)tK * 128 + col;
  const unsigned short* gp = gu + (size_t)grow * TWOI + gcol;
  const float inv = 127.0f / fmaxf(mx[grow], 1e-30f);
  u16x8 ga0 = *reinterpret_cast<const u16x8*>(gp);
  u16x8 ga1 = *reinterpret_cast<const u16x8*>(gp + 8);
  u16x8 ua0 = *reinterpret_cast<const u16x8*>(gp + INTER);
  u16x8 ua1 = *reinterpret_cast<const u16x8*>(gp + INTER + 8);
  i32x4 o;
#pragma unroll
  for (int q = 0; q < 4; ++q) {
    uint32_t d = 0;
#pragma unroll
    for (int b = 0; b < 4; ++b) {
      const int j = q * 4 + b;
      uint32_t gB = (j < 8) ? ga0[j] : ga1[j - 8];
      uint32_t uB = (j < 8) ? ua0[j] : ua1[j - 8];
      float gf = __uint_as_float(gB << 16);
      float uf = __uint_as_float(uB << 16);
      float a = (gf / (1.f + __expf(-gf))) * uf;
      float r = rintf(a * inv);
      r = fminf(fmaxf(r, -127.f), 127.f);
      d |= ((uint32_t)((int)r & 255)) << (8 * b);
    }
    o[q] = (int)d;
  }
  *reinterpret_cast<i32x4*>(q2t + tile * 16384 + (long)within * 16) = o;
}

// ---------------------------------------------------------------------------
extern "C" void kernel_launch(void* const* d_in, const int* in_sizes, int n_in,
                              void* d_out, int out_size, void* d_ws, size_t ws_size,
                              hipStream_t stream)
{
  const int*   x_q = (const int*)d_in[0];
  const float* xs  = (const float*)d_in[1];
  const int*   wg  = (const int*)d_in[2];
  const float* wgs = (const float*)d_in[3];
  const int*   wd  = (const int*)d_in[4];
  const float* wds = (const float*)d_in[5];
  float* out = (float*)d_out;

  uint8_t* ws = (uint8_t*)d_ws;
  uint8_t* x8t  = ws;                                   //   8,388,608
  uint8_t* wg8t = x8t + 8388608;                        //  90,177,536
  uint8_t* wd8t = wg8t + 90177536;                      //  45,088,768
  unsigned short* gu = (unsigned short*)(wd8t + 45088768); // 90,177,536
  float* mx = (float*)((uint8_t*)gu + 90177536);        //       8,192
  uint8_t* q2t = (uint8_t*)mx + 8192;                   //  22,544,384
  // total ~256.4 MB

  pack_tiled<<<2048, 256, 0, stream>>>(x_q, x8t, HID, KT1);
  pack_tiled<<<22016, 256, 0, stream>>>(wg, wg8t, HID, KT1);
  pack_tiled<<<11008, 256, 0, stream>>>(wd, wd8t, INTER, KT2);

  gemm1_k<<<dim3(MTI, NT1), 256, 0, stream>>>(x8t, wg8t, xs, wgs, gu);
  rowmax_k<<<N_TOK, 256, 0, stream>>>(gu, mx);
  quant_k<<<5504, 256, 0, stream>>>(gu, mx, q2t);
  gemm2_k<<<dim3(MTI, NT2), 256, 0, stream>>>(q2t, wd8t, mx, wds, out);
}